// Round 19
// baseline (192.594 us; speedup 1.0000x reference)
//
#include <hip/hip_runtime.h>
#include <math.h>

// SpaceFillingVQ: N=65536 rows, D=64, E=4096 entries.
// bf16-split (3-term) distance pass on 32x32x16 MFMA (4061 vs 3378 FLOP/cyc,
// -17% MFMA issue cycles), 8 waves x 512 threads (VGPR cap 256 kills the
// spill failure mode), 32 rows/wave, E in 2 slices (16 waves/CU). Aux
// kernels identical to r18 (163.7us verified). Exact rescue for gap < TAU.

constexpr int D = 64;
constexpr int CHUNK = 64;           // codebook entries staged per iteration
constexpr int E_PAD = 4096;
constexpr int ESLICES = 2;
constexpr int SLICE = E_PAD / ESLICES;  // 2048 entries per slice
constexpr int NCH = SLICE / CHUNK;      // 32 chunks per slice
constexpr float TAU = 0.005f;       // dist-domain gap threshold for rescue
constexpr int BLK = 512;            // 8 waves; each wave owns 32 rows
constexpr int ROWS_PER_BLOCK = 256;

typedef __attribute__((ext_vector_type(8))) short bf16x8;
typedef __attribute__((ext_vector_type(4))) float f32x4;
typedef __attribute__((ext_vector_type(16))) float f32x16;

__device__ inline unsigned short f2bf(float x) {  // round-to-nearest-even bf16
  unsigned int u = __float_as_uint(x);
  u = (u + 0x7fffu + ((u >> 16) & 1u)) >> 16;
  return (unsigned short)u;
}
__device__ inline float bf2f(unsigned short h) {
  return __uint_as_float(((unsigned int)h) << 16);
}

__device__ __forceinline__ void gll16(const void* g, void* l) {
  __builtin_amdgcn_global_load_lds(
      (const __attribute__((address_space(1))) unsigned int*)g,
      (__attribute__((address_space(3))) unsigned int*)l, 16, 0, 0);
}
__device__ __forceinline__ void gll4(const void* g, void* l) {
  __builtin_amdgcn_global_load_lds(
      (const __attribute__((address_space(1))) unsigned int*)g,
      (__attribute__((address_space(3))) unsigned int*)l, 4, 0, 0);
}

// ---------------- Kernel 1: dithered codebook (f32 + bf16 hi/lo split) + c2/2 ----
__global__ __launch_bounds__(256) void build_kernel(
    const float* __restrict__ cb, const float* __restrict__ dither,
    float* __restrict__ dcb, unsigned short* __restrict__ dcbh,
    unsigned short* __restrict__ dcbl, float* __restrict__ c2h,
    float* __restrict__ counts, int* __restrict__ rescue_n, int E, int Em1) {
  int i = blockIdx.x * 4 + (threadIdx.x >> 6);
  int k = threadIdx.x & 63;
  if (k == 0) counts[i] = 0.0f;
  if (i == 0 && k == 1) *rescue_n = 0;
  if (i >= Em1) {  // pad entries: never selectable
    dcb[(size_t)i * D + k] = 0.f;
    dcbh[(size_t)i * D + k] = 0;
    dcbl[(size_t)i * D + k] = 0;
    if (k == 0) c2h[i] = 3.0e38f;
    return;
  }
  float frac = dither[i] + (float)i;  // replicate reference f32 arithmetic
  int ii = (int)floorf(frac);
  ii = max(0, min(ii, E - 2));
  float r = frac - (float)ii;
  float v = (1.0f - r) * cb[(size_t)ii * D + k] + r * cb[(size_t)(ii + 1) * D + k];
  dcb[(size_t)i * D + k] = v;
  unsigned short h = f2bf(v);
  unsigned short l = f2bf(v - bf2f(h));
  dcbh[(size_t)i * D + k] = h;
  dcbl[(size_t)i * D + k] = l;
  float s = v * v;
#pragma unroll
  for (int off = 32; off > 0; off >>= 1) s += __shfl_down(s, off, 64);
  if (k == 0) c2h[i] = 0.5f * s;
}

// ---------------- Kernel 2: 32x32x16-MFMA distance over one E-slice -----------
// grid (N/256, 2); block 512 = 8 waves; 32 rows/wave; per 64-chunk each wave
// does 2 tiles x 12 MFMA (3 terms x 4 K-steps) into one f32x16 acc.
__global__ __launch_bounds__(BLK) void vq_mfma_kernel(
    const float* __restrict__ X, const unsigned short* __restrict__ dcbh,
    const unsigned short* __restrict__ dcbl, const float* __restrict__ c2h,
    float* __restrict__ out_b1, int* __restrict__ out_i1,
    float* __restrict__ out_b2, int N) {
  __shared__ unsigned short s_h[2][CHUNK * D];
  __shared__ unsigned short s_l[2][CHUNK * D];
  __shared__ float s_c2[2][CHUNK];

  const int tid = threadIdx.x;
  const int lane = tid & 63;
  const int wv = tid >> 6;     // 0..7
  const int col = lane & 31;   // entry-col within 32 (B col / A row)
  const int kh = lane >> 5;    // k-half selector
  const int slice = blockIdx.y;
  const int sbase = slice * SLICE;
  const int wvbase = blockIdx.x * ROWS_PER_BLOCK + wv * 32;

  // ---- A fragments: row = wvbase+col, k = kh*8 + s*16 + i (A/B same k-map
  // -> result invariant to HW internal k-labeling; same trick as 16x16 kernel)
  bf16x8 ah[4], al[4];
  {
    const float* xp = X + (size_t)(wvbase + col) * D + kh * 8;
#pragma unroll
    for (int s = 0; s < 4; ++s)
#pragma unroll
      for (int i = 0; i < 8; ++i) {
        float x = xp[s * 16 + i];
        unsigned short h = f2bf(x);
        ah[s][i] = (short)h;
        al[s][i] = (short)f2bf(x - bf2f(h));
      }
  }

  float b1[16], b2[16];
  int i1[16];
#pragma unroll
  for (int r = 0; r < 16; ++r) { b1[r] = -3.4e38f; b2[r] = -3.4e38f; i1[r] = sbase; }

  const int xs = col & 7;  // XOR-swizzle key (el&7 == col&7 since tile*32 % 8 == 0)

  // staging: pre-swizzled GLOBAL source + linear LDS dest (rule #21).
  // 512 16B-units per chunk per array; wave wv covers unit u = wv*64 + lane.
  auto stage = [&](int ch, int buf) {
    const int u = wv * 64 + lane;
    const int e = u >> 3, g = u & 7;
    const size_t goff = (((size_t)(sbase + ch * CHUNK + e)) << 6) + ((g ^ (e & 7)) << 3);
    gll16(dcbh + goff, (char*)s_h[buf] + (size_t)wv * 1024);  // +lane*16 by HW
    gll16(dcbl + goff, (char*)s_l[buf] + (size_t)wv * 1024);
    if (wv == 0) {  // wave-uniform branch; 64 floats
      gll4(c2h + sbase + ch * CHUNK + lane, (char*)s_c2[buf]);
    }
  };

  stage(0, 0);
  __syncthreads();  // drains vmcnt -> buf0 valid
  int cur = 0;

  for (int ch = 0; ch < NCH; ++ch) {
    const int ebase = sbase + ch * CHUNK;
    if (ch + 1 < NCH) stage(ch + 1, cur ^ 1);  // prefetch hides under MFMA below

#pragma unroll
    for (int t = 0; t < 2; ++t) {  // two 32-entry tiles per chunk
      const int el = t * 32 + col;
      const float hc2 = s_c2[cur][el];
      const int colg = ebase + el;
      const char* bb = (const char*)s_h[cur] + el * 128;
      const char* ll = (const char*)s_l[cur] + el * 128;

      f32x16 acc;
#pragma unroll
      for (int r = 0; r < 16; ++r) acc[r] = -hc2;  // all 16 rows share this col's c2

      __builtin_amdgcn_s_setprio(1);
#pragma unroll
      for (int s = 0; s < 4; ++s) {  // K-steps of 16
        const int g = kh + 2 * s;
        bf16x8 Bh = *(const bf16x8*)(bb + ((g ^ xs) << 4));
        bf16x8 Bl = *(const bf16x8*)(ll + ((g ^ xs) << 4));
        acc = __builtin_amdgcn_mfma_f32_32x32x16_bf16(ah[s], Bh, acc, 0, 0, 0);
        acc = __builtin_amdgcn_mfma_f32_32x32x16_bf16(ah[s], Bl, acc, 0, 0, 0);
        acc = __builtin_amdgcn_mfma_f32_32x32x16_bf16(al[s], Bh, acc, 0, 0, 0);
      }
      __builtin_amdgcn_s_setprio(0);

#pragma unroll
      for (int r = 0; r < 16; ++r) {
        float sv = acc[r];
        bool gt = sv > b1[r];  // strict > -> first occurrence
        b2[r] = __builtin_amdgcn_fmed3f(b2[r], sv, b1[r]);  // b2<=b1 invariant
        b1[r] = fmaxf(b1[r], sv);
        i1[r] = gt ? colg : i1[r];
      }
    }

    __syncthreads();  // drains vmcnt(0): prefetch landed; lgkm: reads done
    cur ^= 1;
  }

  // cross-lane reduce over 32 cols (xor within lane&31; kh preserved)
#pragma unroll
  for (int m = 1; m < 32; m <<= 1) {
#pragma unroll
    for (int r = 0; r < 16; ++r) {
      float ob1 = __shfl_xor(b1[r], m, 64);
      float ob2 = __shfl_xor(b2[r], m, 64);
      int oi1 = __shfl_xor(i1[r], m, 64);
      float loser = fminf(b1[r], ob1);
      b2[r] = fmaxf(fmaxf(b2[r], ob2), loser);
      bool take = (ob1 > b1[r]) || (ob1 == b1[r] && oi1 < i1[r]);
      b1[r] = take ? ob1 : b1[r];
      i1[r] = take ? oi1 : i1[r];
    }
  }
  if (col == 0) {
#pragma unroll
    for (int r = 0; r < 16; ++r) {
      // verified 32x32 C/D map: row = (reg&3) + 8*(reg>>2) + 4*(lane>>5)
      int row = wvbase + (r & 3) + 8 * (r >> 2) + 4 * kh;
      size_t o = (size_t)slice * N + row;
      out_b1[o] = b1[r];
      out_i1[o] = i1[r];
      out_b2[o] = b2[r];
    }
  }
}

// ---------------- Kernel 3: merge slices, histogram, float4 gather ------------
__global__ __launch_bounds__(64) void finish_kernel(
    const float* __restrict__ out_b1, const int* __restrict__ out_i1,
    const float* __restrict__ out_b2,
    const float* __restrict__ dcb, float* __restrict__ outq,
    float* __restrict__ outidx, float* __restrict__ counts,
    int* __restrict__ rescue_n, int* __restrict__ rescue_list, int N) {
  __shared__ int s_idx[64];
  const int lane = threadIdx.x;
  const int rowbase = blockIdx.x * 64;
  const int row = rowbase + lane;

  // ascending slice order + strict > preserves first-occurrence argmin
  float b1c = out_b1[row];
  int bi = out_i1[row];
  float b2c = out_b2[row];
#pragma unroll
  for (int k = 1; k < ESLICES; ++k) {
    float sk = out_b1[(size_t)k * N + row];
    int ek = out_i1[(size_t)k * N + row];
    float qk = out_b2[(size_t)k * N + row];
    b2c = fmaxf(fmaxf(b2c, qk), fminf(sk, b1c));
    bool take = sk > b1c;
    b1c = take ? sk : b1c;
    bi = take ? ek : bi;
  }
  float gap2 = 2.0f * (b1c - b2c);

  outidx[row] = (float)bi;  // tentative for flagged rows; rescue overwrites
  s_idx[lane] = bi;
  if (gap2 < TAU) {
    int p = atomicAdd(rescue_n, 1);
    rescue_list[p] = row;
  } else {
    atomicAdd(&counts[bi], 1.0f);  // exact sums of 1.0f
  }
  __syncthreads();

  // float4 gather: 16 iterations, 4 rows x 16 lanes each; nontemporal stores
  const f32x4* dcb4 = (const f32x4*)dcb;
  f32x4* outq4 = (f32x4*)outq;
  const int rl = lane >> 4;      // row within quad
  const int c4 = lane & 15;      // float4 column
#pragma unroll 4
  for (int t = 0; t < 16; ++t) {
    const int rloc = t * 4 + rl;
    const int idx = s_idx[rloc];
    f32x4 v = dcb4[(size_t)idx * 16 + c4];
    __builtin_nontemporal_store(v, &outq4[(size_t)(rowbase + rloc) * 16 + c4]);
  }
}

// ---------------- Kernel 4: single-dispatch exact rescue (block per row) ------
__global__ __launch_bounds__(256) void rescue_kernel(
    const float* __restrict__ X, const float* __restrict__ dcb,
    const float* __restrict__ c2h, const int* __restrict__ rescue_n,
    const int* __restrict__ rescue_list, float* __restrict__ outq,
    float* __restrict__ outidx, float* __restrict__ counts, int Em1) {
  __shared__ float sx[D];
  __shared__ float sd[4];
  __shared__ int si[4];
  __shared__ int sbest;
  const int tid = threadIdx.x;
  const int nr = *rescue_n;
  for (int li = blockIdx.x; li < nr; li += gridDim.x) {
    const int row = rescue_list[li];
    __syncthreads();  // protect sx/sbest reuse across iterations
    if (tid < D) sx[tid] = X[(size_t)row * D + tid];
    __syncthreads();

    float best = 3.4e38f;
    int bidx = 0x7fffffff;
    for (int e = tid; e < Em1; e += 256) {  // ascending per thread -> first-min ok
      const float4* cp = (const float4*)(dcb + (size_t)e * D);
      float d0 = 0.f, d1 = 0.f, d2 = 0.f, d3 = 0.f;
#pragma unroll
      for (int k = 0; k < 16; ++k) {
        float4 c = cp[k];
        d0 = fmaf(sx[k * 4 + 0], c.x, d0);
        d1 = fmaf(sx[k * 4 + 1], c.y, d1);
        d2 = fmaf(sx[k * 4 + 2], c.z, d2);
        d3 = fmaf(sx[k * 4 + 3], c.w, d3);
      }
      float d = c2h[e] - ((d0 + d1) + (d2 + d3));  // monotone in true distance
      if (d < best) { best = d; bidx = e; }
    }
#pragma unroll
    for (int m = 1; m < 64; m <<= 1) {
      float od = __shfl_xor(best, m, 64);
      int oi = __shfl_xor(bidx, m, 64);
      if (od < best || (od == best && oi < bidx)) { best = od; bidx = oi; }
    }
    if ((tid & 63) == 0) { sd[tid >> 6] = best; si[tid >> 6] = bidx; }
    __syncthreads();
    if (tid == 0) {
      float bb = sd[0]; int bi2 = si[0];
      for (int w = 1; w < 4; ++w)
        if (sd[w] < bb || (sd[w] == bb && si[w] < bi2)) { bb = sd[w]; bi2 = si[w]; }
      sbest = bi2;
      outidx[row] = (float)bi2;
      atomicAdd(&counts[bi2], 1.0f);
    }
    __syncthreads();
    const int bfin = sbest;
    if (tid < D) outq[(size_t)row * D + tid] = dcb[(size_t)bfin * D + tid];
  }
}

// ---------------- Kernel 5: perplexity ----------------------------------------
__global__ __launch_bounds__(256) void vq_perp_kernel(
    const float* __restrict__ counts, float* __restrict__ out, int E, float invN) {
  __shared__ float red[4];
  float s = 0.f;
  for (int j = threadIdx.x; j < E; j += 256) {
    float p = counts[j] * invN;
    s += p * logf(p + 1e-10f);
  }
#pragma unroll
  for (int off = 32; off > 0; off >>= 1) s += __shfl_down(s, off, 64);
  int wid = threadIdx.x >> 6;
  if ((threadIdx.x & 63) == 0) red[wid] = s;
  __syncthreads();
  if (threadIdx.x == 0) {
    float t = (red[0] + red[1]) + (red[2] + red[3]);
    out[0] = expf(-t);
  }
}

static inline size_t align256(size_t x) { return (x + 255) & ~(size_t)255; }

extern "C" void kernel_launch(void* const* d_in, const int* in_sizes, int n_in,
                              void* d_out, int out_size, void* d_ws, size_t ws_size,
                              hipStream_t stream) {
  const float* X      = (const float*)d_in[0];
  const float* cb     = (const float*)d_in[1];
  const float* dither = (const float*)d_in[2];

  const int N   = in_sizes[0] / D;  // 65536
  const int E   = in_sizes[1] / D;  // 4096
  const int Em1 = in_sizes[2];      // 4095

  char* w = (char*)d_ws;
  float* dcb            = (float*)w;          w += align256((size_t)E_PAD * D * sizeof(float));
  unsigned short* dcbh  = (unsigned short*)w; w += align256((size_t)E_PAD * D * sizeof(short));
  unsigned short* dcbl  = (unsigned short*)w; w += align256((size_t)E_PAD * D * sizeof(short));
  float* c2h            = (float*)w;          w += align256((size_t)E_PAD * sizeof(float));
  float* out_b1         = (float*)w;          w += align256((size_t)ESLICES * N * sizeof(float));
  int* out_i1           = (int*)w;            w += align256((size_t)ESLICES * N * sizeof(int));
  float* out_b2         = (float*)w;          w += align256((size_t)ESLICES * N * sizeof(float));
  float* counts         = (float*)w;          w += align256((size_t)E_PAD * sizeof(float));
  int* rescue_n         = (int*)w;            w += align256(sizeof(int));
  int* rescue_list      = (int*)w;            w += align256((size_t)N * sizeof(int));

  float* outq   = (float*)d_out;
  float* perp   = (float*)d_out + (size_t)N * D;
  float* outidx = (float*)d_out + (size_t)N * D + 1;

  build_kernel<<<E_PAD / 4, 256, 0, stream>>>(cb, dither, dcb, dcbh, dcbl, c2h,
                                              counts, rescue_n, E, Em1);

  dim3 g2(N / ROWS_PER_BLOCK, ESLICES);
  vq_mfma_kernel<<<g2, BLK, 0, stream>>>(X, dcbh, dcbl, c2h, out_b1, out_i1, out_b2, N);

  finish_kernel<<<N / 64, 64, 0, stream>>>(out_b1, out_i1, out_b2, dcb, outq, outidx,
                                           counts, rescue_n, rescue_list, N);

  rescue_kernel<<<2048, 256, 0, stream>>>(X, dcb, c2h, rescue_n, rescue_list,
                                          outq, outidx, counts, Em1);

  vq_perp_kernel<<<1, 256, 0, stream>>>(counts, perp, E, 1.0f / (float)N);
}

// Round 20
// 163.619 us; speedup vs baseline: 1.1771x; 1.1771x over previous
//
#include <hip/hip_runtime.h>
#include <math.h>

// SpaceFillingVQ: N=65536 rows, D=64, E=4096 entries.
// REVERT to r18 verified-best (163.7us): bf16-split (3-term) MFMA distance
// pass (r13 16x16 structure — 118us/VGPR64/0-conflict, 7x reproduced; r19's
// 32x32 tile hit a 4-way LDS bank conflict per read and is abandoned).
// TAU=0.005, nontemporal outq stores, block-per-row exact rescue.

constexpr int D = 64;
constexpr int CHUNK = 64;           // codebook entries staged per iteration
constexpr int NTILES = CHUNK / 16;  // 4 MFMA tiles per chunk (2 pairs)
constexpr int E_PAD = 4096;
constexpr int ESLICES = 2;
constexpr int SLICE = E_PAD / ESLICES;  // 2048 entries per slice
constexpr int NCH = SLICE / CHUNK;      // 32 chunks per slice
constexpr float TAU = 0.005f;       // dist-domain gap threshold for rescue
constexpr int BLK = 256;            // 4 waves; each wave owns 32 rows

typedef __attribute__((ext_vector_type(8))) short bf16x8;
typedef __attribute__((ext_vector_type(4))) float f32x4;

__device__ inline unsigned short f2bf(float x) {  // round-to-nearest-even bf16
  unsigned int u = __float_as_uint(x);
  u = (u + 0x7fffu + ((u >> 16) & 1u)) >> 16;
  return (unsigned short)u;
}
__device__ inline float bf2f(unsigned short h) {
  return __uint_as_float(((unsigned int)h) << 16);
}

__device__ __forceinline__ void gll16(const void* g, void* l) {
  __builtin_amdgcn_global_load_lds(
      (const __attribute__((address_space(1))) unsigned int*)g,
      (__attribute__((address_space(3))) unsigned int*)l, 16, 0, 0);
}
__device__ __forceinline__ void gll4(const void* g, void* l) {
  __builtin_amdgcn_global_load_lds(
      (const __attribute__((address_space(1))) unsigned int*)g,
      (__attribute__((address_space(3))) unsigned int*)l, 4, 0, 0);
}

// ---------------- Kernel 1: dithered codebook (f32 + bf16 hi/lo split) + c2/2 ----
// 256-thread blocks, 4 entries/block (one per wave). Also zeroes counts/rescue_n.
__global__ __launch_bounds__(256) void build_kernel(
    const float* __restrict__ cb, const float* __restrict__ dither,
    float* __restrict__ dcb, unsigned short* __restrict__ dcbh,
    unsigned short* __restrict__ dcbl, float* __restrict__ c2h,
    float* __restrict__ counts, int* __restrict__ rescue_n, int E, int Em1) {
  int i = blockIdx.x * 4 + (threadIdx.x >> 6);
  int k = threadIdx.x & 63;
  if (k == 0) counts[i] = 0.0f;
  if (i == 0 && k == 1) *rescue_n = 0;
  if (i >= Em1) {  // pad entries: never selectable
    dcb[(size_t)i * D + k] = 0.f;
    dcbh[(size_t)i * D + k] = 0;
    dcbl[(size_t)i * D + k] = 0;
    if (k == 0) c2h[i] = 3.0e38f;
    return;
  }
  float frac = dither[i] + (float)i;  // replicate reference f32 arithmetic
  int ii = (int)floorf(frac);
  ii = max(0, min(ii, E - 2));
  float r = frac - (float)ii;
  float v = (1.0f - r) * cb[(size_t)ii * D + k] + r * cb[(size_t)(ii + 1) * D + k];
  dcb[(size_t)i * D + k] = v;
  unsigned short h = f2bf(v);
  unsigned short l = f2bf(v - bf2f(h));
  dcbh[(size_t)i * D + k] = h;
  dcbl[(size_t)i * D + k] = l;
  float s = v * v;
#pragma unroll
  for (int off = 32; off > 0; off >>= 1) s += __shfl_down(s, off, 64);
  if (k == 0) c2h[i] = 0.5f * s;
}

// ---------------- Kernel 2: MFMA distance over one E-slice (r13 EXACT) --------
__global__ __launch_bounds__(BLK, 4) void vq_mfma_kernel(
    const float* __restrict__ X, const unsigned short* __restrict__ dcbh,
    const unsigned short* __restrict__ dcbl, const float* __restrict__ c2h,
    float* __restrict__ out_b1, int* __restrict__ out_i1,
    float* __restrict__ out_b2, int N) {
  __shared__ unsigned short s_h[2][CHUNK * D];
  __shared__ unsigned short s_l[2][CHUNK * D];
  __shared__ float s_c2[2][CHUNK];

  const int tid = threadIdx.x;
  const int lane = tid & 63;
  const int wv = tid >> 6;
  const int col = lane & 15;   // MFMA col / A-row within 16
  const int kg = lane >> 4;    // k-group 0..3
  const int slice = blockIdx.y;
  const int sbase = slice * SLICE;
  const int wvbase = blockIdx.x * 128 + wv * 32;

  // ---- A fragments for 2 row-groups: bf16 hi/lo, 2 K-halves (k 0-31, 32-63)
  bf16x8 ah0[2], ah1[2], al0[2], al1[2];
#pragma unroll
  for (int rg = 0; rg < 2; ++rg) {
    const float* xp = X + (size_t)(wvbase + rg * 16 + col) * D + kg * 8;
#pragma unroll
    for (int i = 0; i < 8; ++i) {
      float x0 = xp[i], x1 = xp[32 + i];
      unsigned short h0 = f2bf(x0), h1 = f2bf(x1);
      ah0[rg][i] = (short)h0; ah1[rg][i] = (short)h1;
      al0[rg][i] = (short)f2bf(x0 - bf2f(h0));
      al1[rg][i] = (short)f2bf(x1 - bf2f(h1));
    }
  }

  float b1[2][4], b2[2][4];
  int i1[2][4];
#pragma unroll
  for (int rg = 0; rg < 2; ++rg)
#pragma unroll
    for (int r = 0; r < 4; ++r) { b1[rg][r] = -3.4e38f; b2[rg][r] = -3.4e38f; i1[rg][r] = sbase; }

  const int xs = col & 7;  // XOR-swizzle key (entry&7 within tile == col&7)

  // staging: pre-swizzled GLOBAL source + linear LDS dest (rule #21).
  auto stage = [&](int ch, int buf) {
#pragma unroll
    for (int i = 0; i < 2; ++i) {
      const int u = (wv * 2 + i) * 64 + lane;
      const int e = u >> 3, g = u & 7;
      const size_t goff = (((size_t)(sbase + ch * CHUNK + e)) << 6) + ((g ^ (e & 7)) << 3);
      char* dst_h = (char*)s_h[buf] + (size_t)(wv * 2 + i) * 1024;  // +lane*16 by HW
      char* dst_l = (char*)s_l[buf] + (size_t)(wv * 2 + i) * 1024;
      gll16(dcbh + goff, dst_h);
      gll16(dcbl + goff, dst_l);
    }
    if (wv == 0) {  // wave-uniform branch; 64 floats
      gll4(c2h + sbase + ch * CHUNK + lane, (char*)s_c2[buf]);
    }
  };

  stage(0, 0);
  __syncthreads();  // drains vmcnt -> buf0 valid
  int cur = 0;

  for (int ch = 0; ch < NCH; ++ch) {
    const int ebase = sbase + ch * CHUNK;
    if (ch + 1 < NCH) stage(ch + 1, cur ^ 1);  // prefetch hides under MFMA below

#pragma unroll
    for (int p = 0; p < 2; ++p) {  // tile pairs {0,1}, {2,3}
      bf16x8 Bh0[2], Bh1[2], Bl0[2], Bl1[2];
      float hc2[2];
#pragma unroll
      for (int q = 0; q < 2; ++q) {
        const int el = (p * 2 + q) * 16 + col;
        const char* bb = (const char*)s_h[cur] + el * 128;
        const char* ll = (const char*)s_l[cur] + el * 128;
        Bh0[q] = *(const bf16x8*)(bb + ((kg ^ xs) << 4));
        Bh1[q] = *(const bf16x8*)(bb + (((kg + 4) ^ xs) << 4));
        Bl0[q] = *(const bf16x8*)(ll + ((kg ^ xs) << 4));
        Bl1[q] = *(const bf16x8*)(ll + (((kg + 4) ^ xs) << 4));
        hc2[q] = s_c2[cur][el];
      }
      f32x4 acc[2][2];
#pragma unroll
      for (int q = 0; q < 2; ++q)
#pragma unroll
        for (int rg = 0; rg < 2; ++rg)
          acc[q][rg] = {-hc2[q], -hc2[q], -hc2[q], -hc2[q]};  // s = acc directly
      __builtin_amdgcn_s_setprio(1);
#pragma unroll
      for (int q = 0; q < 2; ++q)
#pragma unroll
        for (int rg = 0; rg < 2; ++rg) {
          acc[q][rg] = __builtin_amdgcn_mfma_f32_16x16x32_bf16(ah0[rg], Bh0[q], acc[q][rg], 0, 0, 0);
          acc[q][rg] = __builtin_amdgcn_mfma_f32_16x16x32_bf16(ah1[rg], Bh1[q], acc[q][rg], 0, 0, 0);
          acc[q][rg] = __builtin_amdgcn_mfma_f32_16x16x32_bf16(ah0[rg], Bl0[q], acc[q][rg], 0, 0, 0);
          acc[q][rg] = __builtin_amdgcn_mfma_f32_16x16x32_bf16(ah1[rg], Bl1[q], acc[q][rg], 0, 0, 0);
          acc[q][rg] = __builtin_amdgcn_mfma_f32_16x16x32_bf16(al0[rg], Bh0[q], acc[q][rg], 0, 0, 0);
          acc[q][rg] = __builtin_amdgcn_mfma_f32_16x16x32_bf16(al1[rg], Bh1[q], acc[q][rg], 0, 0, 0);
        }
      __builtin_amdgcn_s_setprio(0);
#pragma unroll
      for (int q = 0; q < 2; ++q) {
        const int colg = ebase + (p * 2 + q) * 16 + col;
#pragma unroll
        for (int rg = 0; rg < 2; ++rg)
#pragma unroll
          for (int r = 0; r < 4; ++r) {
            float s = acc[q][rg][r];
            bool gt = s > b1[rg][r];  // strict > -> first occurrence
            b2[rg][r] = __builtin_amdgcn_fmed3f(b2[rg][r], s, b1[rg][r]);  // b2<=b1
            b1[rg][r] = fmaxf(b1[rg][r], s);
            i1[rg][r] = gt ? colg : i1[rg][r];
          }
      }
    }

    __syncthreads();  // drains vmcnt(0): prefetch landed; lgkm: reads done
    cur ^= 1;
  }

  // cross-lane reduce over 16 cols (xor within lane&15; same row group = lane>>4)
#pragma unroll
  for (int m = 1; m < 16; m <<= 1) {
#pragma unroll
    for (int rg = 0; rg < 2; ++rg)
#pragma unroll
      for (int r = 0; r < 4; ++r) {
        float ob1 = __shfl_xor(b1[rg][r], m, 64);
        float ob2 = __shfl_xor(b2[rg][r], m, 64);
        int oi1 = __shfl_xor(i1[rg][r], m, 64);
        float loser = fminf(b1[rg][r], ob1);
        b2[rg][r] = fmaxf(fmaxf(b2[rg][r], ob2), loser);
        bool take = (ob1 > b1[rg][r]) || (ob1 == b1[rg][r] && oi1 < i1[rg][r]);
        b1[rg][r] = take ? ob1 : b1[rg][r];
        i1[rg][r] = take ? oi1 : i1[rg][r];
      }
  }
  if (col == 0) {
#pragma unroll
    for (int rg = 0; rg < 2; ++rg)
#pragma unroll
      for (int r = 0; r < 4; ++r) {
        int row = wvbase + rg * 16 + kg * 4 + r;  // row=(lane>>4)*4+reg (C/D map)
        size_t o = (size_t)slice * N + row;
        out_b1[o] = b1[rg][r];
        out_i1[o] = i1[rg][r];
        out_b2[o] = b2[rg][r];
      }
  }
}

// ---------------- Kernel 3: merge slices, histogram, float4 gather ------------
__global__ __launch_bounds__(64) void finish_kernel(
    const float* __restrict__ out_b1, const int* __restrict__ out_i1,
    const float* __restrict__ out_b2,
    const float* __restrict__ dcb, float* __restrict__ outq,
    float* __restrict__ outidx, float* __restrict__ counts,
    int* __restrict__ rescue_n, int* __restrict__ rescue_list, int N) {
  __shared__ int s_idx[64];
  const int lane = threadIdx.x;
  const int rowbase = blockIdx.x * 64;
  const int row = rowbase + lane;

  // ascending slice order + strict > preserves first-occurrence argmin
  float b1c = out_b1[row];
  int bi = out_i1[row];
  float b2c = out_b2[row];
#pragma unroll
  for (int k = 1; k < ESLICES; ++k) {
    float sk = out_b1[(size_t)k * N + row];
    int ek = out_i1[(size_t)k * N + row];
    float qk = out_b2[(size_t)k * N + row];
    b2c = fmaxf(fmaxf(b2c, qk), fminf(sk, b1c));
    bool take = sk > b1c;
    b1c = take ? sk : b1c;
    bi = take ? ek : bi;
  }
  float gap2 = 2.0f * (b1c - b2c);

  outidx[row] = (float)bi;  // tentative for flagged rows; rescue overwrites
  s_idx[lane] = bi;
  if (gap2 < TAU) {
    int p = atomicAdd(rescue_n, 1);
    rescue_list[p] = row;
  } else {
    atomicAdd(&counts[bi], 1.0f);  // exact sums of 1.0f
  }
  __syncthreads();

  // float4 gather: 16 iterations, 4 rows x 16 lanes each; nontemporal stores
  const f32x4* dcb4 = (const f32x4*)dcb;
  f32x4* outq4 = (f32x4*)outq;
  const int rl = lane >> 4;      // row within quad
  const int c4 = lane & 15;      // float4 column
#pragma unroll 4
  for (int t = 0; t < 16; ++t) {
    const int rloc = t * 4 + rl;
    const int idx = s_idx[rloc];
    f32x4 v = dcb4[(size_t)idx * 16 + c4];
    __builtin_nontemporal_store(v, &outq4[(size_t)(rowbase + rloc) * 16 + c4]);
  }
}

// ---------------- Kernel 4: single-dispatch exact rescue (block per row) ------
__global__ __launch_bounds__(256) void rescue_kernel(
    const float* __restrict__ X, const float* __restrict__ dcb,
    const float* __restrict__ c2h, const int* __restrict__ rescue_n,
    const int* __restrict__ rescue_list, float* __restrict__ outq,
    float* __restrict__ outidx, float* __restrict__ counts, int Em1) {
  __shared__ float sx[D];
  __shared__ float sd[4];
  __shared__ int si[4];
  __shared__ int sbest;
  const int tid = threadIdx.x;
  const int nr = *rescue_n;
  for (int li = blockIdx.x; li < nr; li += gridDim.x) {
    const int row = rescue_list[li];
    __syncthreads();  // protect sx/sbest reuse across iterations
    if (tid < D) sx[tid] = X[(size_t)row * D + tid];
    __syncthreads();

    float best = 3.4e38f;
    int bidx = 0x7fffffff;
    for (int e = tid; e < Em1; e += 256) {  // ascending per thread -> first-min ok
      const float4* cp = (const float4*)(dcb + (size_t)e * D);
      float d0 = 0.f, d1 = 0.f, d2 = 0.f, d3 = 0.f;
#pragma unroll
      for (int k = 0; k < 16; ++k) {
        float4 c = cp[k];
        d0 = fmaf(sx[k * 4 + 0], c.x, d0);
        d1 = fmaf(sx[k * 4 + 1], c.y, d1);
        d2 = fmaf(sx[k * 4 + 2], c.z, d2);
        d3 = fmaf(sx[k * 4 + 3], c.w, d3);
      }
      float d = c2h[e] - ((d0 + d1) + (d2 + d3));  // monotone in true distance
      if (d < best) { best = d; bidx = e; }
    }
#pragma unroll
    for (int m = 1; m < 64; m <<= 1) {
      float od = __shfl_xor(best, m, 64);
      int oi = __shfl_xor(bidx, m, 64);
      if (od < best || (od == best && oi < bidx)) { best = od; bidx = oi; }
    }
    if ((tid & 63) == 0) { sd[tid >> 6] = best; si[tid >> 6] = bidx; }
    __syncthreads();
    if (tid == 0) {
      float bb = sd[0]; int bi2 = si[0];
      for (int w = 1; w < 4; ++w)
        if (sd[w] < bb || (sd[w] == bb && si[w] < bi2)) { bb = sd[w]; bi2 = si[w]; }
      sbest = bi2;
      outidx[row] = (float)bi2;
      atomicAdd(&counts[bi2], 1.0f);
    }
    __syncthreads();
    const int bfin = sbest;
    if (tid < D) outq[(size_t)row * D + tid] = dcb[(size_t)bfin * D + tid];
  }
}

// ---------------- Kernel 5: perplexity ----------------------------------------
__global__ __launch_bounds__(256) void vq_perp_kernel(
    const float* __restrict__ counts, float* __restrict__ out, int E, float invN) {
  __shared__ float red[4];
  float s = 0.f;
  for (int j = threadIdx.x; j < E; j += 256) {
    float p = counts[j] * invN;
    s += p * logf(p + 1e-10f);
  }
#pragma unroll
  for (int off = 32; off > 0; off >>= 1) s += __shfl_down(s, off, 64);
  int wid = threadIdx.x >> 6;
  if ((threadIdx.x & 63) == 0) red[wid] = s;
  __syncthreads();
  if (threadIdx.x == 0) {
    float t = (red[0] + red[1]) + (red[2] + red[3]);
    out[0] = expf(-t);
  }
}

static inline size_t align256(size_t x) { return (x + 255) & ~(size_t)255; }

extern "C" void kernel_launch(void* const* d_in, const int* in_sizes, int n_in,
                              void* d_out, int out_size, void* d_ws, size_t ws_size,
                              hipStream_t stream) {
  const float* X      = (const float*)d_in[0];
  const float* cb     = (const float*)d_in[1];
  const float* dither = (const float*)d_in[2];

  const int N   = in_sizes[0] / D;  // 65536
  const int E   = in_sizes[1] / D;  // 4096
  const int Em1 = in_sizes[2];      // 4095

  char* w = (char*)d_ws;
  float* dcb            = (float*)w;          w += align256((size_t)E_PAD * D * sizeof(float));
  unsigned short* dcbh  = (unsigned short*)w; w += align256((size_t)E_PAD * D * sizeof(short));
  unsigned short* dcbl  = (unsigned short*)w; w += align256((size_t)E_PAD * D * sizeof(short));
  float* c2h            = (float*)w;          w += align256((size_t)E_PAD * sizeof(float));
  float* out_b1         = (float*)w;          w += align256((size_t)ESLICES * N * sizeof(float));
  int* out_i1           = (int*)w;            w += align256((size_t)ESLICES * N * sizeof(int));
  float* out_b2         = (float*)w;          w += align256((size_t)ESLICES * N * sizeof(float));
  float* counts         = (float*)w;          w += align256((size_t)E_PAD * sizeof(float));
  int* rescue_n         = (int*)w;            w += align256(sizeof(int));
  int* rescue_list      = (int*)w;            w += align256((size_t)N * sizeof(int));

  float* outq   = (float*)d_out;
  float* perp   = (float*)d_out + (size_t)N * D;
  float* outidx = (float*)d_out + (size_t)N * D + 1;

  build_kernel<<<E_PAD / 4, 256, 0, stream>>>(cb, dither, dcb, dcbh, dcbl, c2h,
                                              counts, rescue_n, E, Em1);

  dim3 g2(N / 128, ESLICES);
  vq_mfma_kernel<<<g2, BLK, 0, stream>>>(X, dcbh, dcbl, c2h, out_b1, out_i1, out_b2, N);

  finish_kernel<<<N / 64, 64, 0, stream>>>(out_b1, out_i1, out_b2, dcb, outq, outidx,
                                           counts, rescue_n, rescue_list, N);

  rescue_kernel<<<2048, 256, 0, stream>>>(X, dcb, c2h, rescue_n, rescue_list,
                                          outq, outidx, counts, Em1);

  vq_perp_kernel<<<1, 256, 0, stream>>>(counts, perp, E, 1.0f / (float)N);
}